// Round 2
// baseline (353.657 us; speedup 1.0000x reference)
//
#include <hip/hip_runtime.h>
#include <hip/hip_fp16.h>

#define BB   128
#define NN   4096
#define OUTD 64
#define P1   64
#define P2   128
#define P3   256
#define R1   256
#define R2   128
#define CHUNK 64
#define NC    4       // 64-pt chunks per block -> grid.x = 4096/256 = 16

typedef _Float16 half8 __attribute__((ext_vector_type(8)));
typedef _Float16 half4 __attribute__((ext_vector_type(4)));
typedef float    f32x4 __attribute__((ext_vector_type(4)));

// workspace layout
#define AGG_OFF 0                        // 128*256 u32 (fp32 bits) = 131072 B
#define W2F_OFF (BB * P3 * 4)            // W2 A-frags fp16, 16 frags x 1KB = 16384 B
#define W3F_OFF (W2F_OFF + P2 * P1 * 2)  // W3 A-frags fp16, 64 frags x 1KB = 65536 B

// prep: zero agg + swizzle w2/w3 into MFMA A-fragment order.
// frag layout: element (l, j) of frag f holds W[ch = mt*16 + (l&15)][k = ks*32 + (l>>4)*8 + j]
__global__ void prep_kernel(const float* __restrict__ w2, const float* __restrict__ w3,
                            unsigned char* ws) {
  int idx = blockIdx.x * 256 + threadIdx.x;
  if (idx < BB * P3) ((unsigned*)(ws + AGG_OFF))[idx] = 0u;   // agg = +0.0f
  _Float16* W2F = (_Float16*)(ws + W2F_OFF);
  _Float16* W3F = (_Float16*)(ws + W3F_OFF);
  if (idx < P1 * P2) {                       // 8192 elements, 16 frags (mt:8, ks:2)
    int f = idx >> 9, rem = idx & 511, l = rem >> 3, j = rem & 7;
    int mt = f >> 1, ks = f & 1;
    int ch = mt * 16 + (l & 15), k = ks * 32 + (l >> 4) * 8 + j;
    W2F[idx] = (_Float16)w2[k * P2 + ch];
  }
  int i2 = idx - P1 * P2;
  if (i2 >= 0 && i2 < P2 * P3) {             // 32768 elements, 64 frags (mt:16, ks:4)
    int f = i2 >> 9, rem = i2 & 511, l = rem >> 3, j = rem & 7;
    int mt = f >> 2, ks = f & 3;
    int ch = mt * 16 + (l & 15), k = ks * 32 + (l >> 4) * 8 + j;
    W3F[i2] = (_Float16)w3[k * P3 + ch];
  }
}

// phi, transposed: h^T with weights as A-operand (register-resident / L2-direct).
// M = channels, N = points. LDS only for h1^T, h2^T in fragment-major [kc][p][8].
__launch_bounds__(256, 3)
__global__ void phi_kernel(const float* __restrict__ pts, const int* __restrict__ lengths,
                           const float* __restrict__ w1, const float* __restrict__ b1,
                           const float* __restrict__ b2, const float* __restrict__ b3,
                           unsigned char* ws) {
  __shared__ __align__(16) _Float16 sH1[2][8][CHUNK][8];   // 16 KB (double-buffered)
  __shared__ __align__(16) _Float16 sH2[16][CHUNK][8];     // 16 KB

  int b    = blockIdx.y;
  int base = blockIdx.x * (CHUNK * NC);
  int len  = lengths[b];
  if (base >= len) return;                        // block-uniform
  int nch = min(NC, (len - base + CHUNK - 1) >> 6);

  int t = threadIdx.x;
  int w = t >> 6, l = t & 63;
  int ml = l & 15, q = l >> 4;

  const half8* W2F = (const half8*)(ws + W2F_OFF);  // 64 half8 per frag
  const half8* W3F = (const half8*)(ws + W3F_OFF);

  // persistent: W2 A-frags (wave w owns ch-tiles 2w, 2w+1), biases, running max
  half8 a2[2][2];
#pragma unroll
  for (int mt2 = 0; mt2 < 2; ++mt2)
#pragma unroll
    for (int ks = 0; ks < 2; ++ks)
      a2[mt2][ks] = W2F[((w * 2 + mt2) * 2 + ks) * 64 + l];
  float b2r[2][4], b3r[4][4];
#pragma unroll
  for (int mt2 = 0; mt2 < 2; ++mt2)
#pragma unroll
    for (int r = 0; r < 4; ++r) b2r[mt2][r] = b2[(w * 2 + mt2) * 16 + q * 4 + r];
#pragma unroll
  for (int s = 0; s < 4; ++s)
#pragma unroll
    for (int r = 0; r < 4; ++r) b3r[s][r] = b3[(w * 4 + s) * 16 + q * 4 + r];
  float rmax[4][4] = {};

  const float2* Pp = (const float2*)pts + (size_t)b * NN + base;

  for (int c = 0; c < nch; ++c) {
    int v = min(CHUNK, len - base - c * CHUNK);
    int buf = c & 1;

    // ---- L1 (K=2, VALU fp32): wave w computes ch [16w,16w+16) for all 64 pts
    {
      float2 xy = Pp[c * CHUNK + l];
      half8 h8[2];
#pragma unroll
      for (int j = 0; j < 16; ++j) {
        int jj = w * 16 + j;                            // wave-uniform -> s_loads
        float h = fmaf(xy.y, w1[P1 + jj], fmaf(xy.x, w1[jj], b1[jj]));
        h8[j >> 3][j & 7] = (_Float16)fmaxf(h, 0.f);
      }
      *(half8*)&sH1[buf][w * 2][l][0]     = h8[0];
      *(half8*)&sH1[buf][w * 2 + 1][l][0] = h8[1];
    }
    __syncthreads();

    // ---- L2: h2^T[128 ch][64 p] = W2^T x h1^T
    f32x4 acc2[2][4] = {};
    {
      half8 bf[4][2];
#pragma unroll
      for (int nt = 0; nt < 4; ++nt)
#pragma unroll
        for (int ks = 0; ks < 2; ++ks)
          bf[nt][ks] = *(const half8*)&sH1[buf][ks * 4 + q][nt * 16 + ml][0];
#pragma unroll
      for (int ks = 0; ks < 2; ++ks)
#pragma unroll
        for (int mt2 = 0; mt2 < 2; ++mt2)
#pragma unroll
          for (int nt = 0; nt < 4; ++nt)
            acc2[mt2][nt] = __builtin_amdgcn_mfma_f32_16x16x32_f16(
                a2[mt2][ks], bf[nt][ks], acc2[mt2][nt], 0, 0, 0);
    }
    // epilogue: bias+ReLU, lane holds 4 consecutive ch -> packed b64 writes
#pragma unroll
    for (int mt2 = 0; mt2 < 2; ++mt2)
#pragma unroll
      for (int nt = 0; nt < 4; ++nt) {
        half4 hp;
#pragma unroll
        for (int r = 0; r < 4; ++r)
          hp[r] = (_Float16)fmaxf(acc2[mt2][nt][r] + b2r[mt2][r], 0.f);
        *(half4*)&sH2[(w * 2 + mt2) * 2 + (q >> 1)][nt * 16 + ml][(q & 1) * 4] = hp;
      }
    __syncthreads();

    // ---- L3: h3^T[256 ch][64 p] = W3^T x h2^T, 4 slabs (wave w: mt = w*4+s)
    half8 a3c[4], a3n[4];
#pragma unroll
    for (int ks = 0; ks < 4; ++ks) a3c[ks] = W3F[((w * 4) * 4 + ks) * 64 + l];
    for (int s = 0; s < 4; ++s) {
      if (s < 3) {
#pragma unroll
        for (int ks = 0; ks < 4; ++ks)
          a3n[ks] = W3F[((w * 4 + s + 1) * 4 + ks) * 64 + l];
      }
      f32x4 acc3[4] = {};
#pragma unroll
      for (int ks = 0; ks < 4; ++ks)
#pragma unroll
        for (int nt = 0; nt < 4; ++nt) {
          half8 bf = *(const half8*)&sH2[ks * 4 + q][nt * 16 + ml][0];
          acc3[nt] = __builtin_amdgcn_mfma_f32_16x16x32_f16(
              a3c[ks], bf, acc3[nt], 0, 0, 0);
        }
#pragma unroll
      for (int nt = 0; nt < 4; ++nt)
#pragma unroll
        for (int r = 0; r < 4; ++r) {
          float val = fmaxf(acc3[nt][r] + b3r[s][r], 0.f);
          if (nt * 16 + ml < v) rmax[s][r] = fmaxf(rmax[s][r], val);
        }
#pragma unroll
      for (int ks = 0; ks < 4; ++ks) a3c[ks] = a3n[ks];
    }
  }

  // block-end: reduce running max across ml lanes, one atomic per channel
  unsigned* aggU = (unsigned*)(ws + AGG_OFF) + b * P3;
#pragma unroll
  for (int s = 0; s < 4; ++s)
#pragma unroll
    for (int r = 0; r < 4; ++r) {
      float m = rmax[s][r];
      m = fmaxf(m, __shfl_xor(m, 1));
      m = fmaxf(m, __shfl_xor(m, 2));
      m = fmaxf(m, __shfl_xor(m, 4));
      m = fmaxf(m, __shfl_xor(m, 8));
      if (ml == 0)
        atomicMax(&aggU[(w * 4 + s) * 16 + q * 4 + r], __float_as_uint(m));
    }
}

// rho MLP, fp32, one block per batch row
__global__ void rho_kernel(const unsigned char* __restrict__ ws,
                           const float* __restrict__ r1w, const float* __restrict__ r1b,
                           const float* __restrict__ r2w, const float* __restrict__ r2b,
                           const float* __restrict__ r3w, const float* __restrict__ r3b,
                           float* __restrict__ out) {
  __shared__ float sa[R1], sz1[R1], sz2[R2];
  int b = blockIdx.x, t = threadIdx.x;
  const float* agg = (const float*)(ws + AGG_OFF) + b * P3;
  sa[t] = agg[t];
  __syncthreads();
  float a1 = r1b[t];
#pragma unroll 8
  for (int k = 0; k < P3; ++k) a1 = fmaf(sa[k], r1w[k * R1 + t], a1);
  sz1[t] = fmaxf(a1, 0.f);
  __syncthreads();
  if (t < R2) {
    float a2 = r2b[t];
#pragma unroll 8
    for (int k = 0; k < R1; ++k) a2 = fmaf(sz1[k], r2w[k * R2 + t], a2);
    sz2[t] = fmaxf(a2, 0.f);
  }
  __syncthreads();
  if (t < OUTD) {
    float a3 = r3b[t];
#pragma unroll 8
    for (int k = 0; k < R2; ++k) a3 = fmaf(sz2[k], r3w[k * OUTD + t], a3);
    out[b * OUTD + t] = a3;
  }
}

extern "C" void kernel_launch(void* const* d_in, const int* in_sizes, int n_in,
                              void* d_out, int out_size, void* d_ws, size_t ws_size,
                              hipStream_t stream) {
  const float* pts     = (const float*)d_in[0];
  const int*   lengths = (const int*)d_in[1];
  const float* w1  = (const float*)d_in[2];
  const float* b1  = (const float*)d_in[3];
  const float* w2  = (const float*)d_in[4];
  const float* b2  = (const float*)d_in[5];
  const float* w3  = (const float*)d_in[6];
  const float* b3  = (const float*)d_in[7];
  const float* r1w = (const float*)d_in[8];
  const float* r1b = (const float*)d_in[9];
  const float* r2w = (const float*)d_in[10];
  const float* r2b = (const float*)d_in[11];
  const float* r3w = (const float*)d_in[12];
  const float* r3b = (const float*)d_in[13];
  unsigned char* ws = (unsigned char*)d_ws;

  prep_kernel<<<160, 256, 0, stream>>>(w2, w3, ws);
  phi_kernel<<<dim3(NN / (CHUNK * NC), BB), 256, 0, stream>>>(pts, lengths, w1, b1, b2, b3, ws);
  rho_kernel<<<BB, 256, 0, stream>>>(ws, r1w, r1b, r2w, r2b, r3w, r3b, (float*)d_out);
}

// Round 3
// 145.883 us; speedup vs baseline: 2.4242x; 2.4242x over previous
//
#include <hip/hip_runtime.h>
#include <hip/hip_fp16.h>

#define BB   128
#define NN   4096
#define OUTD 64
#define P1   64
#define P2   128
#define P3   256
#define R1   256
#define R2   128
#define CHUNK 64

typedef _Float16 half8 __attribute__((ext_vector_type(8)));
typedef _Float16 half4 __attribute__((ext_vector_type(4)));
typedef float    f32x4 __attribute__((ext_vector_type(4)));

// workspace layout
#define AGG_OFF 0                        // 128*256 u32 (fp32 bits) = 131072 B
#define W2F_OFF (BB * P3 * 4)            // W2 A-frags fp16, 16 frags x 1KB = 16384 B
#define W3F_OFF (W2F_OFF + P2 * P1 * 2)  // W3 A-frags fp16, 64 frags x 1KB = 65536 B

// prep: zero agg + swizzle w2/w3 into MFMA A-fragment order.
// frag f element (l, j): W[ch = mt*16 + (l&15)][k = ks*32 + (l>>4)*8 + j]
__global__ void prep_kernel(const float* __restrict__ w2, const float* __restrict__ w3,
                            unsigned char* ws) {
  int idx = blockIdx.x * 256 + threadIdx.x;
  if (idx < BB * P3) ((unsigned*)(ws + AGG_OFF))[idx] = 0u;   // agg = +0.0f
  _Float16* W2F = (_Float16*)(ws + W2F_OFF);
  _Float16* W3F = (_Float16*)(ws + W3F_OFF);
  if (idx < P1 * P2) {                       // 16 frags (mt:8, ks:2)
    int f = idx >> 9, rem = idx & 511, l = rem >> 3, j = rem & 7;
    int mt = f >> 1, ks = f & 1;
    int ch = mt * 16 + (l & 15), k = ks * 32 + (l >> 4) * 8 + j;
    W2F[idx] = (_Float16)w2[k * P2 + ch];
  }
  int i2 = idx - P1 * P2;
  if (i2 >= 0 && i2 < P2 * P3) {             // 64 frags (mt:16, ks:4)
    int f = i2 >> 9, rem = i2 & 511, l = rem >> 3, j = rem & 7;
    int mt = f >> 2, ks = f & 3;
    int ch = mt * 16 + (l & 15), k = ks * 32 + (l >> 4) * 8 + j;
    W3F[i2] = (_Float16)w3[k * P3 + ch];
  }
}

// phi: one block = one (batch, 64-pt chunk). Transposed (h^T), weights as
// register A-frags from L2. LDS = 24 KB (h1^T + h2^T, fragment-major).
// No persistent cross-chunk state -> no spill (R2 post-mortem).
__launch_bounds__(256, 3)
__global__ void phi_kernel(const float* __restrict__ pts, const int* __restrict__ lengths,
                           const float* __restrict__ w1, const float* __restrict__ b1,
                           const float* __restrict__ b2, const float* __restrict__ b3,
                           unsigned char* ws) {
  __shared__ __align__(16) _Float16 sH1[8][CHUNK][8];    //  8 KB
  __shared__ __align__(16) _Float16 sH2[16][CHUNK][8];   // 16 KB

  int b  = blockIdx.y;
  int c0 = blockIdx.x * CHUNK;
  int len = lengths[b];
  if (c0 >= len) return;                  // block-uniform
  int v = min(CHUNK, len - c0);

  int t = threadIdx.x;
  int w = t >> 6, l = t & 63;
  int ml = l & 15, q = l >> 4;

  const half8* W2F = (const half8*)(ws + W2F_OFF);  // 64 half8 per frag
  const half8* W3F = (const half8*)(ws + W3F_OFF);

  // issue W2 frags (wave w: ch-tiles 2w,2w+1) and W3 slab-0 frags early
  half8 a2[2][2];
#pragma unroll
  for (int mt2 = 0; mt2 < 2; ++mt2)
#pragma unroll
    for (int ks = 0; ks < 2; ++ks)
      a2[mt2][ks] = W2F[((w * 2 + mt2) * 2 + ks) * 64 + l];
  half8 a3c[4];
#pragma unroll
  for (int ks = 0; ks < 4; ++ks)
    a3c[ks] = W3F[((w * 4 + 0) * 4 + ks) * 64 + l];

  // ---- L1 (K=2, VALU fp32): wave w computes ch [16w,16w+16) for all 64 pts
  {
    const float2* Pp = (const float2*)pts + (size_t)b * NN + c0;
    float2 xy = Pp[l];
    half8 h8[2];
#pragma unroll
    for (int j = 0; j < 16; ++j) {
      int jj = w * 16 + j;                              // wave-uniform -> s_loads
      float h = fmaf(xy.y, w1[P1 + jj], fmaf(xy.x, w1[jj], b1[jj]));
      h8[j >> 3][j & 7] = (_Float16)fmaxf(h, 0.f);
    }
    *(half8*)&sH1[w * 2][l][0]     = h8[0];
    *(half8*)&sH1[w * 2 + 1][l][0] = h8[1];
  }
  __syncthreads();

  // ---- L2: h2^T[128][64] = W2^T x h1^T  (16 MFMAs/wave)
  {
    f32x4 acc2[2][4] = {};
#pragma unroll
    for (int ks = 0; ks < 2; ++ks) {
      half8 bf[4];
#pragma unroll
      for (int nt = 0; nt < 4; ++nt)
        bf[nt] = *(const half8*)&sH1[ks * 4 + q][nt * 16 + ml][0];
#pragma unroll
      for (int mt2 = 0; mt2 < 2; ++mt2)
#pragma unroll
        for (int nt = 0; nt < 4; ++nt)
          acc2[mt2][nt] = __builtin_amdgcn_mfma_f32_16x16x32_f16(
              a2[mt2][ks], bf[nt], acc2[mt2][nt], 0, 0, 0);
    }
    // epilogue: bias+ReLU; lane holds 4 consecutive ch -> packed 8B writes
#pragma unroll
    for (int mt2 = 0; mt2 < 2; ++mt2) {
      float4 b2v = *(const float4*)&b2[(w * 2 + mt2) * 16 + q * 4];
#pragma unroll
      for (int nt = 0; nt < 4; ++nt) {
        half4 hp;
        hp[0] = (_Float16)fmaxf(acc2[mt2][nt][0] + b2v.x, 0.f);
        hp[1] = (_Float16)fmaxf(acc2[mt2][nt][1] + b2v.y, 0.f);
        hp[2] = (_Float16)fmaxf(acc2[mt2][nt][2] + b2v.z, 0.f);
        hp[3] = (_Float16)fmaxf(acc2[mt2][nt][3] + b2v.w, 0.f);
        *(half4*)&sH2[(w * 2 + mt2) * 2 + (q >> 1)][nt * 16 + ml][(q & 1) * 4] = hp;
      }
    }
  }
  __syncthreads();

  // ---- L3: h3^T[256][64] = W3^T x h2^T, 4 slabs/wave (mt = w*4+s), 64 MFMAs
  unsigned* aggU = (unsigned*)(ws + AGG_OFF) + b * P3;
  for (int s = 0; s < 4; ++s) {
    half8 a3n[4];
    if (s < 3) {
#pragma unroll
      for (int ks = 0; ks < 4; ++ks)
        a3n[ks] = W3F[((w * 4 + s + 1) * 4 + ks) * 64 + l];
    }
    float4 b3v = *(const float4*)&b3[(w * 4 + s) * 16 + q * 4];
    f32x4 acc3[4] = {};
#pragma unroll
    for (int ks = 0; ks < 4; ++ks)
#pragma unroll
      for (int nt = 0; nt < 4; ++nt) {
        half8 bf = *(const half8*)&sH2[ks * 4 + q][nt * 16 + ml][0];
        acc3[nt] = __builtin_amdgcn_mfma_f32_16x16x32_f16(
            a3c[ks], bf, acc3[nt], 0, 0, 0);
      }
    // bias+ReLU+validity, max over this wave's 64 points, atomic per channel
    float rm[4] = {0.f, 0.f, 0.f, 0.f};
    float bb[4] = {b3v.x, b3v.y, b3v.z, b3v.w};
#pragma unroll
    for (int nt = 0; nt < 4; ++nt) {
      bool ok = (nt * 16 + ml) < v;
#pragma unroll
      for (int r = 0; r < 4; ++r) {
        float val = fmaxf(acc3[nt][r] + bb[r], 0.f);
        if (ok) rm[r] = fmaxf(rm[r], val);
      }
    }
#pragma unroll
    for (int r = 0; r < 4; ++r) {
      float m = rm[r];
      m = fmaxf(m, __shfl_xor(m, 1));
      m = fmaxf(m, __shfl_xor(m, 2));
      m = fmaxf(m, __shfl_xor(m, 4));
      m = fmaxf(m, __shfl_xor(m, 8));
      if (ml == 0)
        atomicMax(&aggU[(w * 4 + s) * 16 + q * 4 + r], __float_as_uint(m));
    }
#pragma unroll
    for (int ks = 0; ks < 4; ++ks) a3c[ks] = a3n[ks];
  }
}

// rho MLP, fp32, one block per batch row; 4-way split accumulators for ILP
__global__ void rho_kernel(const unsigned char* __restrict__ ws,
                           const float* __restrict__ r1w, const float* __restrict__ r1b,
                           const float* __restrict__ r2w, const float* __restrict__ r2b,
                           const float* __restrict__ r3w, const float* __restrict__ r3b,
                           float* __restrict__ out) {
  __shared__ float sa[R1], sz1[R1], sz2[R2];
  int b = blockIdx.x, t = threadIdx.x;
  const float* agg = (const float*)(ws + AGG_OFF) + b * P3;
  sa[t] = agg[t];
  __syncthreads();
  {
    float p0 = 0.f, p1 = 0.f, p2 = 0.f, p3 = 0.f;
#pragma unroll 8
    for (int k = 0; k < 64; ++k) {
      p0 = fmaf(sa[k],       r1w[k * R1 + t],         p0);
      p1 = fmaf(sa[k + 64],  r1w[(k + 64) * R1 + t],  p1);
      p2 = fmaf(sa[k + 128], r1w[(k + 128) * R1 + t], p2);
      p3 = fmaf(sa[k + 192], r1w[(k + 192) * R1 + t], p3);
    }
    sz1[t] = fmaxf(r1b[t] + ((p0 + p1) + (p2 + p3)), 0.f);
  }
  __syncthreads();
  if (t < R2) {
    float p0 = 0.f, p1 = 0.f, p2 = 0.f, p3 = 0.f;
#pragma unroll 8
    for (int k = 0; k < 64; ++k) {
      p0 = fmaf(sz1[k],       r2w[k * R2 + t],         p0);
      p1 = fmaf(sz1[k + 64],  r2w[(k + 64) * R2 + t],  p1);
      p2 = fmaf(sz1[k + 128], r2w[(k + 128) * R2 + t], p2);
      p3 = fmaf(sz1[k + 192], r2w[(k + 192) * R2 + t], p3);
    }
    sz2[t] = fmaxf(r2b[t] + ((p0 + p1) + (p2 + p3)), 0.f);
  }
  __syncthreads();
  if (t < OUTD) {
    float p0 = 0.f, p1 = 0.f;
#pragma unroll 8
    for (int k = 0; k < 64; ++k) {
      p0 = fmaf(sz2[k],      r3w[k * OUTD + t],        p0);
      p1 = fmaf(sz2[k + 64], r3w[(k + 64) * OUTD + t], p1);
    }
    out[b * OUTD + t] = r3b[t] + p0 + p1;
  }
}

extern "C" void kernel_launch(void* const* d_in, const int* in_sizes, int n_in,
                              void* d_out, int out_size, void* d_ws, size_t ws_size,
                              hipStream_t stream) {
  const float* pts     = (const float*)d_in[0];
  const int*   lengths = (const int*)d_in[1];
  const float* w1  = (const float*)d_in[2];
  const float* b1  = (const float*)d_in[3];
  const float* w2  = (const float*)d_in[4];
  const float* b2  = (const float*)d_in[5];
  const float* w3  = (const float*)d_in[6];
  const float* b3  = (const float*)d_in[7];
  const float* r1w = (const float*)d_in[8];
  const float* r1b = (const float*)d_in[9];
  const float* r2w = (const float*)d_in[10];
  const float* r2b = (const float*)d_in[11];
  const float* r3w = (const float*)d_in[12];
  const float* r3b = (const float*)d_in[13];
  unsigned char* ws = (unsigned char*)d_ws;

  prep_kernel<<<160, 256, 0, stream>>>(w2, w3, ws);
  phi_kernel<<<dim3(NN / CHUNK, BB), 256, 0, stream>>>(pts, lengths, w1, b1, b2, b3, ws);
  rho_kernel<<<BB, 256, 0, stream>>>(ws, r1w, r1b, r2w, r2b, r3w, r3b, (float*)d_out);
}